// Round 5
// baseline (151.894 us; speedup 1.0000x reference)
//
#include <hip/hip_runtime.h>

// Fixed problem shapes
constexpr int B  = 8;
constexpr int C  = 32;
constexpr int H  = 224;
constexpr int Wd = 224;
constexpr int ND = 8;            // num_convs
constexpr int Ho = 222;          // H - 3 + 1
constexpr int Wo = 222;
constexpr int JG = 56;           // ceil(Wo/4) column groups
constexpr int HG = 111;          // Ho/2 row pairs
constexpr unsigned PLANE = (unsigned)Ho * Wo;   // 49284 floats

typedef float vf2  __attribute__((ext_vector_type(2)));
typedef float vf4  __attribute__((ext_vector_type(4)));
// odd output rows: byte offset ≡ 8 mod 16; dense float4 store, 8B-aligned type
typedef float vf4u __attribute__((ext_vector_type(4), aligned(8)));

__global__ __launch_bounds__(256)
void dconv_kernel(const float* __restrict__ x,
                  const float* __restrict__ Wt,
                  const float* __restrict__ Bv,
                  float* __restrict__ out) {
    unsigned gid = blockIdx.x * 256u + threadIdx.x;
    // gid -> (b, d, c, ig, jg); jg fastest => consecutive lanes write
    // consecutive 16B chunks; consecutive blocks write consecutive output
    // addresses (dense moving write front through the whole output buffer).
    unsigned jg = gid % JG;
    unsigned t  = gid / JG;
    unsigned ig = t % HG;  t /= HG;
    unsigned c  = t % C;   t /= C;
    unsigned d  = t % ND;
    unsigned b  = t / ND;
    if (b >= B) return;   // grid divides exactly; kept for safety

    const unsigned i0 = ig * 2u;   // even output row
    const unsigned j0 = jg * 4u;
    const bool edge = (jg == JG - 1);   // j0 == 220: only 2 valid output cols

    // ---- load 4x6 input patch (2 output rows x 4 cols, one conv) ----
    const float* xp = x + (((b * C + c) * H + i0) * Wd + j0);
    float p[4][6];
#pragma unroll
    for (int r = 0; r < 4; ++r) {
        const vf4 v4 = *reinterpret_cast<const vf4*>(xp + r * Wd);
        p[r][0] = v4.x; p[r][1] = v4.y; p[r][2] = v4.z; p[r][3] = v4.w;
        if (!edge) {
            const vf2 v2 = *reinterpret_cast<const vf2*>(xp + r * Wd + 4);
            p[r][4] = v2.x; p[r][5] = v2.y;
        } else {
            p[r][4] = 0.f;  p[r][5] = 0.f;
        }
    }

    // ---- weights for this d: wave-uniform scalar loads ----
    float w[9];
#pragma unroll
    for (int q = 0; q < 9; ++q) w[q] = Wt[d * 9u + q];
    const float bs = Bv[d];

    // ---- compute 2x4 outputs ----
    float a[2][4];
#pragma unroll
    for (int rr = 0; rr < 2; ++rr) {
#pragma unroll
        for (int q = 0; q < 4; ++q) a[rr][q] = bs;
#pragma unroll
        for (int r = 0; r < 3; ++r) {
#pragma unroll
            for (int q = 0; q < 3; ++q) {
                const float wv = w[r * 3 + q];
                a[rr][0] = fmaf(wv, p[rr + r][q + 0], a[rr][0]);
                a[rr][1] = fmaf(wv, p[rr + r][q + 1], a[rr][1]);
                a[rr][2] = fmaf(wv, p[rr + r][q + 2], a[rr][2]);
                a[rr][3] = fmaf(wv, p[rr + r][q + 3], a[rr][3]);
            }
        }
    }

    // ---- store: one plane, 2 dense rows ----
    float* op = out + (((b * ND + d) * C + c) * PLANE + i0 * Wo + j0);
    if (!edge) {
        vf4 s0; s0.x = a[0][0]; s0.y = a[0][1]; s0.z = a[0][2]; s0.w = a[0][3];
        *reinterpret_cast<vf4*>(op) = s0;                  // even row: 16B aligned
        vf4u s1; s1.x = a[1][0]; s1.y = a[1][1]; s1.z = a[1][2]; s1.w = a[1][3];
        *reinterpret_cast<vf4u*>(op + Wo) = s1;            // odd row: 8 mod 16
    } else {
        vf2 s0; s0.x = a[0][0]; s0.y = a[0][1];
        vf2 s1; s1.x = a[1][0]; s1.y = a[1][1];
        *reinterpret_cast<vf2*>(op) = s0;
        *reinterpret_cast<vf2*>(op + Wo) = s1;
    }
}

extern "C" void kernel_launch(void* const* d_in, const int* in_sizes, int n_in,
                              void* d_out, int out_size, void* d_ws, size_t ws_size,
                              hipStream_t stream) {
    const float* x  = (const float*)d_in[0];
    const float* Wt = (const float*)d_in[1];   // [1, ND, 3, 3] flat
    const float* Bv = (const float*)d_in[2];   // [ND]
    float* out      = (float*)d_out;           // [B, ND*C, Ho, Wo]

    const unsigned total  = (unsigned)B * ND * C * HG * JG;  // 12,730,368
    const unsigned blocks = total / 256u;                    // 49,728 exact
    dconv_kernel<<<blocks, 256, 0, stream>>>(x, Wt, Bv, out);
}

// Round 6
// 97.101 us; speedup vs baseline: 1.5643x; 1.5643x over previous
//
#include <hip/hip_runtime.h>

// Fixed problem shapes
constexpr unsigned B  = 8, C = 32, H = 224, Wd = 224, ND = 8;
constexpr unsigned Ho = 222, Wo = 222;
constexpr unsigned PLANE  = Ho * Wo;      // 49284 floats per output plane
constexpr unsigned CHUNKS = PLANE / 4u;   // 12321 float4 chunks (exact)
constexpr unsigned DSTR   = C * PLANE;    // d-plane stride in floats

typedef float vf2 __attribute__((ext_vector_type(2)));
typedef float vf4 __attribute__((ext_vector_type(4)));

// Each thread owns ONE plane-linear float4 chunk (4 consecutive output
// elements, may straddle a row boundary) and computes it for ALL 8 convs.
// => every global store is a 16B-aligned vf4; a wave's 64 lanes write 64
// consecutive chunks = 1KB fully dense per instruction; the 8 output planes
// fill as linear fronts exactly like a fill kernel.
__global__ __launch_bounds__(256)
void dconv_kernel(const float* __restrict__ x,
                  const float* __restrict__ Wt,
                  const float* __restrict__ Bv,
                  float* __restrict__ out) {
    const unsigned gid = blockIdx.x * 256u + threadIdx.x;   // < 3,154,176
    const unsigned bc  = gid / CHUNKS;                      // (b*C + c), 0..255
    const unsigned k   = gid - bc * CHUNKS;                 // chunk in plane
    const unsigned b   = bc >> 5, c = bc & 31u;
    const unsigned fo  = k * 4u;                            // plane float offset
    const unsigned i   = fo / Wo;                           // first output row
    const unsigned jj  = fo - i * Wo;                       // first col (even)

    const float* xrow = x + ((unsigned long)bc * H + i) * Wd;  // input row i
    const bool strad = (jj == 220u);   // chunk spans rows i (cols 220,221) and i+1 (cols 0,1)

    float* const obase = out + (unsigned long)(b * (ND * C) + c) * PLANE + fo;

    if (!strad) {
        // ---- fast path: 3x6 patch, rows i..i+2, cols jj..jj+5 (jj even) ----
        float p[3][6];
#pragma unroll
        for (int r = 0; r < 3; ++r) {
            const float* rp = xrow + r * Wd + jj;
            const vf2 v0 = *reinterpret_cast<const vf2*>(rp);
            const vf2 v1 = *reinterpret_cast<const vf2*>(rp + 2);
            const vf2 v2 = *reinterpret_cast<const vf2*>(rp + 4);
            p[r][0] = v0.x; p[r][1] = v0.y;
            p[r][2] = v1.x; p[r][3] = v1.y;
            p[r][4] = v2.x; p[r][5] = v2.y;
        }
#pragma unroll
        for (int d = 0; d < (int)ND; ++d) {
            float w[9];
#pragma unroll
            for (int q = 0; q < 9; ++q) w[q] = Wt[d * 9 + q];  // uniform s_load
            const float bs = Bv[d];
            float a0 = bs, a1 = bs, a2 = bs, a3 = bs;
#pragma unroll
            for (int r = 0; r < 3; ++r) {
#pragma unroll
                for (int q = 0; q < 3; ++q) {
                    const float wv = w[r * 3 + q];
                    a0 = fmaf(wv, p[r][q + 0], a0);
                    a1 = fmaf(wv, p[r][q + 1], a1);
                    a2 = fmaf(wv, p[r][q + 2], a2);
                    a3 = fmaf(wv, p[r][q + 3], a3);
                }
            }
            vf4 s; s.x = a0; s.y = a1; s.z = a2; s.w = a3;
            *reinterpret_cast<vf4*>(obase + d * DSTR) = s;   // 16B aligned
        }
    } else {
        // ---- straddle path (~1 lane / 2 waves): outputs (i,220),(i,221),
        //      (i+1,0),(i+1,1). Patches: rows i..i+2 @ cols 220..223 and
        //      rows i+1..i+3 @ cols 0..3 (all vf4, 16B aligned). ----
        float s1[3][4], s2[3][4];
#pragma unroll
        for (int r = 0; r < 3; ++r) {
            const vf4 va = *reinterpret_cast<const vf4*>(xrow + r * Wd + 220);
            s1[r][0] = va.x; s1[r][1] = va.y; s1[r][2] = va.z; s1[r][3] = va.w;
            const vf4 vb = *reinterpret_cast<const vf4*>(xrow + (r + 1) * Wd);
            s2[r][0] = vb.x; s2[r][1] = vb.y; s2[r][2] = vb.z; s2[r][3] = vb.w;
        }
#pragma unroll
        for (int d = 0; d < (int)ND; ++d) {
            float w[9];
#pragma unroll
            for (int q = 0; q < 9; ++q) w[q] = Wt[d * 9 + q];
            const float bs = Bv[d];
            float a0 = bs, a1 = bs, a2 = bs, a3 = bs;
#pragma unroll
            for (int r = 0; r < 3; ++r) {
#pragma unroll
                for (int q = 0; q < 3; ++q) {
                    const float wv = w[r * 3 + q];
                    a0 = fmaf(wv, s1[r][q + 0], a0);   // (i,   220)
                    a1 = fmaf(wv, s1[r][q + 1], a1);   // (i,   221)
                    a2 = fmaf(wv, s2[r][q + 0], a2);   // (i+1, 0)
                    a3 = fmaf(wv, s2[r][q + 1], a3);   // (i+1, 1)
                }
            }
            vf4 s; s.x = a0; s.y = a1; s.z = a2; s.w = a3;
            *reinterpret_cast<vf4*>(obase + d * DSTR) = s;
        }
    }
}

extern "C" void kernel_launch(void* const* d_in, const int* in_sizes, int n_in,
                              void* d_out, int out_size, void* d_ws, size_t ws_size,
                              hipStream_t stream) {
    const float* x  = (const float*)d_in[0];
    const float* Wt = (const float*)d_in[1];   // [1, ND, 3, 3] flat
    const float* Bv = (const float*)d_in[2];   // [ND]
    float* out      = (float*)d_out;           // [B, ND*C, Ho, Wo]

    const unsigned total  = B * C * CHUNKS;    // 3,154,176 threads
    const unsigned blocks = total / 256u;      // 12,321 exact
    dconv_kernel<<<blocks, 256, 0, stream>>>(x, Wt, Bv, out);
}

// Round 7
// 94.437 us; speedup vs baseline: 1.6084x; 1.0282x over previous
//
#include <hip/hip_runtime.h>

// Fixed problem shapes
constexpr unsigned B  = 8, C = 32, H = 224, Wd = 224, ND = 8;
constexpr unsigned Ho = 222, Wo = 222;
constexpr unsigned PLANE  = Ho * Wo;      // 49284 floats per output plane
constexpr unsigned CHUNKS = PLANE / 4u;   // 12321 float4 chunks (exact)
constexpr unsigned DSTR   = C * PLANE;    // d-plane stride in floats

typedef float vf2 __attribute__((ext_vector_type(2)));
typedef float vf4 __attribute__((ext_vector_type(4)));

// One thread = one plane-linear float4 output chunk, computed for all 8 convs.
// Phase 1: all input loads (3 dense vf4 + 3 vf2). Phase 2: all 8x4 accumulators
// (weights hoisted to SGPRs once). Phase 3: 8 dense vf4 stores back-to-back so
// each wave emits one 8KB write burst to 8 linear plane fronts.
__global__ __launch_bounds__(256)
void dconv_kernel(const float* __restrict__ x,
                  const float* __restrict__ Wt,
                  const float* __restrict__ Bv,
                  float* __restrict__ out) {
    // ---- weights first: wave-uniform -> one s_load set for the whole kernel
    float w[ND][9];
    float bs[ND];
#pragma unroll
    for (int d = 0; d < (int)ND; ++d) {
#pragma unroll
        for (int q = 0; q < 9; ++q) w[d][q] = Wt[d * 9 + q];
        bs[d] = Bv[d];
    }

    const unsigned gid = blockIdx.x * 256u + threadIdx.x;   // < 3,154,176
    const unsigned bc  = gid / CHUNKS;                      // (b*C + c), 0..255
    const unsigned k   = gid - bc * CHUNKS;                 // chunk in plane
    const unsigned b   = bc >> 5, c = bc & 31u;
    const unsigned fo  = k * 4u;                            // plane float offset
    const unsigned i   = fo / Wo;                           // first output row
    const unsigned jj  = fo - i * Wo;                       // first col (even)

    const float* xrow = x + ((unsigned long)bc * H + i) * Wd;
    const bool strad = (jj == 220u);   // chunk spans rows i and i+1

    float* const obase = out + (unsigned long)(b * (ND * C) + c) * PLANE + fo;

    // ---- Phase 1: input patch ----
    // p[r][0..5]: for non-strad, input cols jj..jj+5 of rows i..i+2.
    // For strad: p[r][0..3] = cols 220..223 of rows i..i+2 (covers outputs
    // (i,220),(i,221)); p[r][4..5] unused; q2[r][0..3] = cols 0..3 of rows
    // i+1..i+3 (covers outputs (i+1,0),(i+1,1)).
    float p[3][6];
    float q2[3][4];
    if (!strad) {
#pragma unroll
        for (int r = 0; r < 3; ++r) {
            const float* rp = xrow + r * Wd + jj;
            const vf4 v4 = *reinterpret_cast<const vf4*>(rp);       // dense 1KB/wave
            const vf2 v2 = *reinterpret_cast<const vf2*>(rp + 4);
            p[r][0] = v4.x; p[r][1] = v4.y; p[r][2] = v4.z; p[r][3] = v4.w;
            p[r][4] = v2.x; p[r][5] = v2.y;
        }
    } else {
#pragma unroll
        for (int r = 0; r < 3; ++r) {
            const vf4 va = *reinterpret_cast<const vf4*>(xrow + r * Wd + 220);
            p[r][0] = va.x; p[r][1] = va.y; p[r][2] = va.z; p[r][3] = va.w;
            p[r][4] = 0.f;  p[r][5] = 0.f;
            const vf4 vb = *reinterpret_cast<const vf4*>(xrow + (r + 1) * Wd);
            q2[r][0] = vb.x; q2[r][1] = vb.y; q2[r][2] = vb.z; q2[r][3] = vb.w;
        }
    }

    // ---- Phase 2: all 8 convs into registers ----
    float a[ND][4];
    if (!strad) {
#pragma unroll
        for (int d = 0; d < (int)ND; ++d) {
            float a0 = bs[d], a1 = bs[d], a2 = bs[d], a3 = bs[d];
#pragma unroll
            for (int r = 0; r < 3; ++r) {
#pragma unroll
                for (int q = 0; q < 3; ++q) {
                    const float wv = w[d][r * 3 + q];
                    a0 = fmaf(wv, p[r][q + 0], a0);
                    a1 = fmaf(wv, p[r][q + 1], a1);
                    a2 = fmaf(wv, p[r][q + 2], a2);
                    a3 = fmaf(wv, p[r][q + 3], a3);
                }
            }
            a[d][0] = a0; a[d][1] = a1; a[d][2] = a2; a[d][3] = a3;
        }
    } else {
#pragma unroll
        for (int d = 0; d < (int)ND; ++d) {
            float a0 = bs[d], a1 = bs[d], a2 = bs[d], a3 = bs[d];
#pragma unroll
            for (int r = 0; r < 3; ++r) {
#pragma unroll
                for (int q = 0; q < 3; ++q) {
                    const float wv = w[d][r * 3 + q];
                    a0 = fmaf(wv, p[r][q + 0], a0);    // (i,   220)
                    a1 = fmaf(wv, p[r][q + 1], a1);    // (i,   221)
                    a2 = fmaf(wv, q2[r][q + 0], a2);   // (i+1, 0)
                    a3 = fmaf(wv, q2[r][q + 1], a3);   // (i+1, 1)
                }
            }
            a[d][0] = a0; a[d][1] = a1; a[d][2] = a2; a[d][3] = a3;
        }
    }

    // ---- Phase 3: 8 dense 16B stores back-to-back (one write burst) ----
#pragma unroll
    for (int d = 0; d < (int)ND; ++d) {
        vf4 s; s.x = a[d][0]; s.y = a[d][1]; s.z = a[d][2]; s.w = a[d][3];
        *reinterpret_cast<vf4*>(obase + (unsigned)d * DSTR) = s;
    }
}

extern "C" void kernel_launch(void* const* d_in, const int* in_sizes, int n_in,
                              void* d_out, int out_size, void* d_ws, size_t ws_size,
                              hipStream_t stream) {
    const float* x  = (const float*)d_in[0];
    const float* Wt = (const float*)d_in[1];   // [1, ND, 3, 3] flat
    const float* Bv = (const float*)d_in[2];   // [ND]
    float* out      = (float*)d_out;           // [B, ND*C, Ho, Wo]

    const unsigned total  = B * C * CHUNKS;    // 3,154,176 threads
    const unsigned blocks = total / 256u;      // 12,321 exact
    dconv_kernel<<<blocks, 256, 0, stream>>>(x, Wt, Bv, out);
}